// Round 6
// baseline (2803.610 us; speedup 1.0000x reference)
//
#include <hip/hip_runtime.h>
#include <hip/hip_bf16.h>
#include <math.h>

// Problem constants (fixed by setup_inputs)
constexpr int kB  = 4;
constexpr int kH  = 128;
constexpr int kW  = 128;
constexpr int kHW = kH * kW;          // 16384
constexpr int kC1 = 256;              // layer1 in channels
constexpr int kM  = 128;              // mid channels
constexpr int kC2 = 256;              // layer2 out channels

typedef unsigned short u16;
typedef unsigned int u32;
typedef _Float16 h16;
typedef __attribute__((ext_vector_type(8))) _Float16 h16x8;
typedef __attribute__((ext_vector_type(4))) float f32x4;
typedef __attribute__((ext_vector_type(4))) int i32x4;

__device__ inline h16 u2h(u16 u) { union { u16 u; h16 h; } c; c.u = u; return c.h; }
__device__ inline u16 h2u(h16 h) { union { u16 u; h16 h; } c; c.h = h; return c.u; }

// ---------------- NCHW f32 -> NHWC fp16 (optionally fused BN+ReLU) ----------
template <bool BN>
__global__ __launch_bounds__(256) void to_nhwc(const float* __restrict__ src,
                                               const float* __restrict__ ss,
                                               u16* __restrict__ dst, int C) {
  int pxg = blockIdx.x * 256 + threadIdx.x;  // 0 .. B*HW-1
  int b = pxg >> 14, p = pxg & 16383;
  const float* sp = src + (size_t)b * C * kHW + p;
  u16* dp = dst + (size_t)pxg * C;
  for (int c = 0; c < C; c += 2) {
    float v0 = sp[(size_t)c * kHW], v1 = sp[(size_t)(c + 1) * kHW];
    if (BN) {
      v0 = fmaxf(fmaf(v0, ss[2 * c], ss[2 * c + 1]), 0.f);
      v1 = fmaxf(fmaf(v1, ss[2 * c + 2], ss[2 * c + 3]), 0.f);
    }
    u32 pk = (u32)h2u((h16)v0) | ((u32)h2u((h16)v1) << 16);
    *(u32*)(dp + c) = pk;
  }
}

// ------------- weight pre-pack into MFMA B-fragment order (fp16) ------------
// layout: [CIN/32][9][ntiles][64 lanes][8] ; k_local = 8*(lane>>4)+j -> channel,
// n = 16*nt + (lane&15)
__global__ __launch_bounds__(256) void prep_bpack(const float* __restrict__ w,
                                                  u16* __restrict__ bp, int CIN,
                                                  int ntiles, int OREAL) {
  int i = blockIdx.x * 256 + threadIdx.x;
  int total = (CIN / 32) * 9 * ntiles * 512;
  if (i >= total) return;
  int j = i & 7, l = (i >> 3) & 63;
  int rest = i >> 9;
  int nt = rest % ntiles; rest /= ntiles;
  int tap = rest % 9;
  int ch = rest / 9;
  int c = ch * 32 + ((l >> 4) << 3) + j;
  int o = nt * 16 + (l & 15);
  float v = (o < OREAL) ? w[((size_t)o * CIN + c) * 9 + tap] : 0.f;
  bp[i] = h2u((h16)v);
}

// ---------------- fused (deformable) conv via MFMA implicit GEMM ------------
// Block: 8x16 px tile, 4 waves, MT=2 (wave = 2 rows x 16 cols), NT n-frags.
// Halo (12x20 px) per 32-ch chunk staged in LDS (double-buffered); bilinear
// gathers served by ds_read_b128; A-fragments built in fp16 registers.
// Sampling plan precomputed once per wave into registers.
constexpr int HR = 12, HC = 20, HSLOT = HR * HC;   // 240 px
constexpr int HBYTES = HSLOT * 64;                 // 15360 B per buffer

template <int CIN, int NTOT, int NT, int OREAL, bool DEFORM>
__global__ __launch_bounds__(256, 2) void dcn_mfma(
    const u16* __restrict__ xt, const float* __restrict__ om,
    const float* __restrict__ boff, const u16* __restrict__ bpack,
    const float* __restrict__ bias, float* __restrict__ y) {
  constexpr int NCH = CIN / 32;
  extern __shared__ char lds[];

  const int tid = threadIdx.x;
  const int lane = tid & 63;
  const int wv = tid >> 6;
  const int col = lane & 15;
  const int cg = lane >> 4;
  const int tile = blockIdx.x, b = blockIdx.y, zb = blockIdx.z;
  const int h0 = (tile >> 3) << 3;    // 16 row-tiles of 8
  const int w0 = (tile & 7) << 4;     // 8 col-tiles of 16
  const u16* xb = xt + (size_t)b * kHW * CIN;

  // ---- sampling plan (registers), once per wave ----
  u32 pA[9][2], pG0[9][2], pG1[9][2];
  if (DEFORM) {
#pragma unroll
    for (int tap = 0; tap < 9; tap++) {
      const int dy = tap / 3 - 1, dx = tap % 3 - 1;
#pragma unroll
      for (int m = 0; m < 2; m++) {
        const int h = h0 + wv * 2 + m, w = w0 + col;
        const float* omb = om + ((size_t)(b * 27 + tap)) * kHW + h * kW + w;
        float offy = omb[0] + boff[tap];
        float offx = omb[(size_t)9 * kHW] + boff[9 + tap];
        float ml = omb[(size_t)18 * kHW] + boff[18 + tap];
        float mask = 1.f / (1.f + expf(-ml));
        float py = (float)(h + dy) + offy;
        float qx = (float)(w + dx) + offx;
        float fy = floorf(py), fx = floorf(qx);
        float lyf = py - fy, lxf = qx - fx;
        int yi = (int)fy, xi = (int)fx;
        bool vy0 = (yi >= 0) & (yi < kH), vy1 = (yi + 1 >= 0) & (yi + 1 < kH);
        bool vx0 = (xi >= 0) & (xi < kW), vx1 = (xi + 1 >= 0) & (xi + 1 < kW);
        float g00 = (vy0 && vx0) ? (1.f - lyf) * (1.f - lxf) * mask : 0.f;
        float g01 = (vy0 && vx1) ? (1.f - lyf) * lxf * mask : 0.f;
        float g10 = (vy1 && vx0) ? lyf * (1.f - lxf) * mask : 0.f;
        float g11 = (vy1 && vx1) ? lyf * lxf * mask : 0.f;
        int ly = yi - (h0 - 2), lx = xi - (w0 - 2);
        pA[tap][m] = (u32)(ly & 0xffff) | ((u32)lx << 16);
        pG0[tap][m] = (u32)h2u((h16)g00) | ((u32)h2u((h16)g01) << 16);
        pG1[tap][m] = (u32)h2u((h16)g10) | ((u32)h2u((h16)g11) << 16);
      }
    }
  }

  f32x4 acc[2][NT];
#pragma unroll
  for (int m = 0; m < 2; m++)
#pragma unroll
    for (int nt = 0; nt < NT; nt++) acc[m][nt] = (f32x4){0.f, 0.f, 0.f, 0.f};

  // ---- staging helpers ----
  auto stage_load = [&](int ch, i32x4* st) {
#pragma unroll
    for (int i = 0; i < 4; i++) {
      int slot = tid + i * 256;
      if (slot < HSLOT * 4) {
        int p = slot >> 2, scg = slot & 3;
        int py = (p * 205) >> 12;          // p / 20 for p < 400
        int pxx = p - py * HC;
        int gy = min(max(h0 - 2 + py, 0), kH - 1);
        int gx = min(max(w0 - 2 + pxx, 0), kW - 1);
        st[i] = *(const i32x4*)(xb + ((size_t)(gy * kW + gx)) * CIN + (ch << 5) +
                                (scg << 3));
      }
    }
  };
  auto stage_write = [&](char* buf, const i32x4* st) {
#pragma unroll
    for (int i = 0; i < 4; i++) {
      int slot = tid + i * 256;
      if (slot < HSLOT * 4) *(i32x4*)(buf + slot * 16) = st[i];
    }
  };

  // ---- main loop over 32-channel chunks ----
  {
    i32x4 st0[4];
    stage_load(0, st0);
    stage_write(lds, st0);
  }
  int cur = 0;
  for (int ch = 0; ch < NCH; ++ch) {
    __syncthreads();
    char* bufc = lds + cur * HBYTES;
    i32x4 st[4];
    const bool has = (ch + 1 < NCH);
    if (has) stage_load(ch + 1, st);

#pragma unroll
    for (int tap = 0; tap < 9; tap++) {
      h16x8 af[2];
      if (DEFORM) {
#pragma unroll
        for (int m = 0; m < 2; m++) {
          int lylx = pA[tap][m];
          int ly = (short)(lylx & 0xffff);
          int lx = ((int)lylx) >> 16;
          h16 g00 = u2h((u16)(pG0[tap][m] & 0xffff));
          h16 g01 = u2h((u16)(pG0[tap][m] >> 16));
          h16 g10 = u2h((u16)(pG1[tap][m] & 0xffff));
          h16 g11 = u2h((u16)(pG1[tap][m] >> 16));
          h16x8 v00, v01, v10, v11;
          if (__builtin_expect(((u32)ly <= (u32)(HR - 2)) &&
                                   ((u32)lx <= (u32)(HC - 2)), 1)) {
            const char* bp8 = bufc + (ly * HC + lx) * 64 + (cg << 4);
            v00 = *(const h16x8*)(bp8);
            v01 = *(const h16x8*)(bp8 + 64);
            v10 = *(const h16x8*)(bp8 + HC * 64);
            v11 = *(const h16x8*)(bp8 + HC * 64 + 64);
          } else {  // rare fallback: global gather with reference clamping
            int y0 = ly + (h0 - 2), x0 = lx + (w0 - 2);
            int y0c = min(max(y0, 0), kH - 1), y1c = min(max(y0 + 1, 0), kH - 1);
            int x0c = min(max(x0, 0), kW - 1), x1c = min(max(x0 + 1, 0), kW - 1);
            const u16* gp = xb + (ch << 5) + (cg << 3);
            v00 = *(const h16x8*)(gp + (size_t)(y0c * kW + x0c) * CIN);
            v01 = *(const h16x8*)(gp + (size_t)(y0c * kW + x1c) * CIN);
            v10 = *(const h16x8*)(gp + (size_t)(y1c * kW + x0c) * CIN);
            v11 = *(const h16x8*)(gp + (size_t)(y1c * kW + x1c) * CIN);
          }
          af[m] = v00 * g00 + v01 * g01 + v10 * g10 + v11 * g11;
        }
      } else {
        const int dy = tap / 3 - 1, dx = tap % 3 - 1;
#pragma unroll
        for (int m = 0; m < 2; m++) {
          const int row = wv * 2 + m;
          int yy = h0 + row + dy, xx = w0 + col + dx;
          bool val = ((u32)yy < (u32)kH) && ((u32)xx < (u32)kW);
          h16x8 v = *(const h16x8*)(bufc + ((row + dy + 2) * HC + col + dx + 2) * 64 +
                                    (cg << 4));
          h16x8 zv = (h16x8){0, 0, 0, 0, 0, 0, 0, 0};
          af[m] = val ? v : zv;
        }
      }
      const u16* bpb = bpack + ((size_t)((ch * 9 + tap) * NTOT) + zb * NT) * 512 +
                       (lane << 3);
#pragma unroll
      for (int nt = 0; nt < NT; nt++) {
        h16x8 bfr = *(const h16x8*)(bpb + (size_t)nt * 512);
        acc[0][nt] = __builtin_amdgcn_mfma_f32_16x16x32_f16(af[0], bfr, acc[0][nt], 0, 0, 0);
        acc[1][nt] = __builtin_amdgcn_mfma_f32_16x16x32_f16(af[1], bfr, acc[1][nt], 0, 0, 0);
      }
    }
    if (has) stage_write(lds + (cur ^ 1) * HBYTES, st);
    cur ^= 1;
  }

  // ---- epilogue: D layout col(n)=lane&15, row(m-in-frag)=4*(lane>>4)+r ----
#pragma unroll
  for (int m = 0; m < 2; m++) {
    const int h = h0 + wv * 2 + m;
#pragma unroll
    for (int nt = 0; nt < NT; nt++) {
      int o = (zb * NT + nt) * 16 + col;
      if (OREAL < NTOT * 16 && o >= OREAL) continue;
      float bb = bias ? bias[o] : 0.f;
#pragma unroll
      for (int r = 0; r < 4; r++) {
        int w = w0 + (cg << 2) + r;
        y[((size_t)(b * OREAL + o)) * kHW + h * kW + w] = acc[m][nt][r] + bb;
      }
    }
  }
}

// ---------------- BN stats (one block per channel) ----------------
__global__ __launch_bounds__(256) void bn_stats(const float* __restrict__ y,
                                                const float* __restrict__ g,
                                                const float* __restrict__ be,
                                                float* __restrict__ ss, int C) {
  const int c = blockIdx.x;
  float s = 0.f, s2 = 0.f;
  for (int b = 0; b < kB; b++) {
    const float4* p = (const float4*)(y + ((size_t)(b * C + c)) * kHW);
    for (int i = threadIdx.x; i < kHW / 4; i += 256) {
      float4 v = p[i];
      s += v.x + v.y + v.z + v.w;
      s2 += v.x * v.x + v.y * v.y + v.z * v.z + v.w * v.w;
    }
  }
#pragma unroll
  for (int o = 32; o > 0; o >>= 1) {
    s += __shfl_down(s, o, 64);
    s2 += __shfl_down(s2, o, 64);
  }
  __shared__ float red[8];
  int lane = threadIdx.x & 63, wid = threadIdx.x >> 6;
  if (lane == 0) {
    red[wid] = s;
    red[4 + wid] = s2;
  }
  __syncthreads();
  if (threadIdx.x == 0) {
    float S = red[0] + red[1] + red[2] + red[3];
    float S2 = red[4] + red[5] + red[6] + red[7];
    const float inv = 1.f / (float)(kB * kHW);
    float mu = S * inv;
    float var = S2 * inv - mu * mu;
    float sc = g[c] * rsqrtf(var + 1e-5f);
    ss[2 * c] = sc;
    ss[2 * c + 1] = be[c] - mu * sc;
  }
}

// ---------------- BN apply + ReLU (final, NCHW in-place) ----------------
__global__ __launch_bounds__(256) void bn_apply(const float* __restrict__ y,
                                                const float* __restrict__ ss,
                                                float* __restrict__ out, int C,
                                                int total4) {
  int idx = blockIdx.x * 256 + threadIdx.x;
  int stride = gridDim.x * 256;
  for (int i = idx; i < total4; i += stride) {
    int c = (i >> 12) % C;
    float sc = ss[2 * c], shf = ss[2 * c + 1];
    float4 v = ((const float4*)y)[i];
    v.x = fmaxf(fmaf(v.x, sc, shf), 0.f);
    v.y = fmaxf(fmaf(v.y, sc, shf), 0.f);
    v.z = fmaxf(fmaf(v.z, sc, shf), 0.f);
    v.w = fmaxf(fmaf(v.w, sc, shf), 0.f);
    ((float4*)out)[i] = v;
  }
}

// ---------------- launch ----------------
extern "C" void kernel_launch(void* const* d_in, const int* in_sizes, int n_in,
                              void* d_out, int out_size, void* d_ws, size_t ws_size,
                              hipStream_t stream) {
  const float* x      = (const float*)d_in[0];
  const float* w_off1 = (const float*)d_in[1];
  const float* b_off1 = (const float*)d_in[2];
  const float* w1     = (const float*)d_in[3];
  const float* b1     = (const float*)d_in[4];
  const float* g1     = (const float*)d_in[5];
  const float* be1    = (const float*)d_in[6];
  const float* w_off2 = (const float*)d_in[7];
  const float* b_off2 = (const float*)d_in[8];
  const float* w2     = (const float*)d_in[9];
  const float* b2     = (const float*)d_in[10];
  const float* g2     = (const float*)d_in[11];
  const float* be2    = (const float*)d_in[12];

  char* ws = (char*)d_ws;
  const size_t XT_OFF  = 0;                        // xt1 (33.5MB); xt2 aliases
  const size_t XT_SZ   = (size_t)kB * kHW * kC1 * 2;
  const size_t OM_OFF  = XT_OFF + XT_SZ;           // 7MB
  const size_t OM_SZ   = (size_t)27 * kB * kHW * 4;
  const size_t BPO1_OFF = OM_OFF + OM_SZ;
  const size_t BPO1_SZ  = (size_t)9 * (kC1 / 32) * 2 * 512 * 2;
  const size_t BP1_OFF = BPO1_OFF + BPO1_SZ;
  const size_t BP1_SZ  = (size_t)9 * (kC1 / 32) * (kM / 16) * 512 * 2;
  const size_t BPO2_OFF = BP1_OFF + BP1_SZ;
  const size_t BPO2_SZ  = (size_t)9 * (kM / 32) * 2 * 512 * 2;
  const size_t BP2_OFF = BPO2_OFF + BPO2_SZ;
  const size_t BP2_SZ  = (size_t)9 * (kM / 32) * (kC2 / 16) * 512 * 2;
  const size_t SS_OFF  = BP2_OFF + BP2_SZ;

  u16* xt1  = (u16*)(ws + XT_OFF);
  u16* xt2  = (u16*)(ws + XT_OFF);  // alias: xt1 dead before xt2 written
  float* om = (float*)(ws + OM_OFF);
  u16* bpo1 = (u16*)(ws + BPO1_OFF);
  u16* bp1  = (u16*)(ws + BP1_OFF);
  u16* bpo2 = (u16*)(ws + BPO2_OFF);
  u16* bp2  = (u16*)(ws + BP2_OFF);
  float* ssb = (float*)(ws + SS_OFF);
  float* y1 = (float*)d_out;
  float* y2 = (float*)d_out;

  const int LDSB = 2 * HBYTES;  // 30720 B

  // ---------- layer 1 ----------
  to_nhwc<false><<<256, 256, 0, stream>>>(x, nullptr, xt1, kC1);
  prep_bpack<<<(9 * 8 * 2 * 512 + 255) / 256, 256, 0, stream>>>(w_off1, bpo1, kC1, 2, 27);
  prep_bpack<<<(9 * 8 * 8 * 512 + 255) / 256, 256, 0, stream>>>(w1, bp1, kC1, 8, kM);
  dcn_mfma<kC1, 2, 2, 27, false><<<dim3(128, kB, 1), 256, LDSB, stream>>>(
      xt1, nullptr, nullptr, bpo1, nullptr, om);
  dcn_mfma<kC1, 8, 8, kM, true><<<dim3(128, kB, 1), 256, LDSB, stream>>>(
      xt1, om, b_off1, bp1, b1, y1);
  bn_stats<<<kM, 256, 0, stream>>>(y1, g1, be1, ssb, kM);
  to_nhwc<true><<<256, 256, 0, stream>>>(y1, ssb, xt2, kM);

  // ---------- layer 2 ----------
  prep_bpack<<<(9 * 4 * 2 * 512 + 255) / 256, 256, 0, stream>>>(w_off2, bpo2, kM, 2, 27);
  prep_bpack<<<(9 * 4 * 16 * 512 + 255) / 256, 256, 0, stream>>>(w2, bp2, kM, 16, kC2);
  dcn_mfma<kM, 2, 2, 27, false><<<dim3(128, kB, 1), 256, LDSB, stream>>>(
      xt2, nullptr, nullptr, bpo2, nullptr, om);
  dcn_mfma<kM, 16, 8, kC2, true><<<dim3(128, kB, 2), 256, LDSB, stream>>>(
      xt2, om, b_off2, bp2, b2, y2);
  bn_stats<<<kC2, 256, 0, stream>>>(y2, g2, be2, ssb, kC2);
  bn_apply<<<2048, 256, 0, stream>>>(y2, ssb, (float*)d_out, kC2, kB * kC2 * kHW / 4);
}

// Round 7
// 570.621 us; speedup vs baseline: 4.9133x; 4.9133x over previous
//
#include <hip/hip_runtime.h>
#include <hip/hip_bf16.h>
#include <math.h>

// Problem constants (fixed by setup_inputs)
constexpr int kB  = 4;
constexpr int kH  = 128;
constexpr int kW  = 128;
constexpr int kHW = kH * kW;          // 16384
constexpr int kC1 = 256;              // layer1 in channels
constexpr int kM  = 128;              // mid channels
constexpr int kC2 = 256;              // layer2 out channels

typedef unsigned short u16;
typedef unsigned int u32;
typedef _Float16 h16;
typedef __attribute__((ext_vector_type(8))) _Float16 h16x8;
typedef __attribute__((ext_vector_type(4))) float f32x4;
typedef __attribute__((ext_vector_type(4))) int i32x4;

__device__ inline h16 u2h(u16 u) { union { u16 u; h16 h; } c; c.u = u; return c.h; }
__device__ inline u16 h2u(h16 h) { union { u16 u; h16 h; } c; c.h = h; return c.u; }

// ---------------- NCHW f32 -> NHWC fp16 (optionally fused BN+ReLU) ----------
template <bool BN>
__global__ __launch_bounds__(256) void to_nhwc(const float* __restrict__ src,
                                               const float* __restrict__ ss,
                                               u16* __restrict__ dst, int C) {
  int pxg = blockIdx.x * 256 + threadIdx.x;  // 0 .. B*HW-1
  int b = pxg >> 14, p = pxg & 16383;
  const float* sp = src + (size_t)b * C * kHW + p;
  u16* dp = dst + (size_t)pxg * C;
  for (int c = 0; c < C; c += 2) {
    float v0 = sp[(size_t)c * kHW], v1 = sp[(size_t)(c + 1) * kHW];
    if (BN) {
      v0 = fmaxf(fmaf(v0, ss[2 * c], ss[2 * c + 1]), 0.f);
      v1 = fmaxf(fmaf(v1, ss[2 * c + 2], ss[2 * c + 3]), 0.f);
    }
    u32 pk = (u32)h2u((h16)v0) | ((u32)h2u((h16)v1) << 16);
    *(u32*)(dp + c) = pk;
  }
}

// ------------- weight pre-pack into MFMA B-fragment order (fp16) ------------
// layout: [CIN/32][9][ntiles][64 lanes][8] ; k_local = 8*(lane>>4)+j -> channel,
// n = 16*nt + (lane&15)
__global__ __launch_bounds__(256) void prep_bpack(const float* __restrict__ w,
                                                  u16* __restrict__ bp, int CIN,
                                                  int ntiles, int OREAL) {
  int i = blockIdx.x * 256 + threadIdx.x;
  int total = (CIN / 32) * 9 * ntiles * 512;
  if (i >= total) return;
  int j = i & 7, l = (i >> 3) & 63;
  int rest = i >> 9;
  int nt = rest % ntiles; rest /= ntiles;
  int tap = rest % 9;
  int ch = rest / 9;
  int c = ch * 32 + ((l >> 4) << 3) + j;
  int o = nt * 16 + (l & 15);
  float v = (o < OREAL) ? w[((size_t)o * CIN + c) * 9 + tap] : 0.f;
  bp[i] = h2u((h16)v);
}

// ---------------- fused (deformable) conv via MFMA implicit GEMM ------------
// Block: 8 rows x 16 cols of pixels; M-dim of MFMA = 16 w-columns; 4 waves own
// 2 rows each (m=0,1). Halo 12x20 px per 32-ch chunk in LDS (double-buffered,
// issue-early/write-late). Sampling plan in LDS [tap][128px][16B], computed
// once per block. A-fragments built in fp16 regs, B streamed from prepacked
// global (L2-hot). acc NT=4 (32 VGPR); no big per-thread arrays -> no scratch.
constexpr int HR = 12, HC = 20, HSLOT = HR * HC;   // 240 px
constexpr int HBYTES = HSLOT * 64;                 // 15360 B per buffer
constexpr int PLAN_OFF = 2 * HBYTES;               // plan after 2 halo buffers
constexpr int LDS_DEF = 2 * HBYTES + 9 * 128 * 16; // 49152 B
constexpr int LDS_IMC = 2 * HBYTES;                // 30720 B

template <int CIN, int NTOT, int NT, int OREAL, bool DEFORM>
__global__ __launch_bounds__(256, 3) void dcn_mfma(
    const u16* __restrict__ xt, const float* __restrict__ om,
    const float* __restrict__ boff, const u16* __restrict__ bpack,
    const float* __restrict__ bias, float* __restrict__ y) {
  constexpr int NCH = CIN / 32;
  extern __shared__ char lds[];

  const int tid = threadIdx.x;
  const int lane = tid & 63;
  const int wv = tid >> 6;
  const int col = lane & 15;
  const int cg = lane >> 4;
  const int tile = blockIdx.x, b = blockIdx.y, zb = blockIdx.z;
  const int h0 = (tile >> 4) << 3;    // 16 row-tiles of 8
  const int w0 = (tile & 15) << 4;    // wait: 8 col-tiles of 16 -> tile&7
  // NOTE: grid.x = 128 tiles: 16 row-tiles x 8 col-tiles
  const int h0r = (tile >> 3) << 3;
  const int w0r = (tile & 7) << 4;
  const u16* xb = xt + (size_t)b * kHW * CIN;

  // ---- sampling plan -> LDS [tap][128 px][16B] ----
  if (DEFORM) {
    i32x4* plan = (i32x4*)(lds + PLAN_OFF);
    for (int e = tid; e < 1152; e += 256) {
      int px = e / 9;                 // pixel id: (row<<4) | colw
      int tap = e - px * 9;
      int h = h0r + (px >> 4), w = w0r + (px & 15);
      const int dy = tap / 3 - 1, dx = tap % 3 - 1;
      const float* omb = om + ((size_t)(b * 27 + tap)) * kHW + h * kW + w;
      float offy = omb[0] + boff[tap];
      float offx = omb[(size_t)9 * kHW] + boff[9 + tap];
      float ml = omb[(size_t)18 * kHW] + boff[18 + tap];
      float mask = 1.f / (1.f + expf(-ml));
      float py = (float)(h + dy) + offy;
      float qx = (float)(w + dx) + offx;
      float fy = floorf(py), fx = floorf(qx);
      float lyf = py - fy, lxf = qx - fx;
      int yi = (int)fy, xi = (int)fx;
      bool vy0 = (yi >= 0) & (yi < kH), vy1 = (yi + 1 >= 0) & (yi + 1 < kH);
      bool vx0 = (xi >= 0) & (xi < kW), vx1 = (xi + 1 >= 0) & (xi + 1 < kW);
      float g00 = (vy0 && vx0) ? (1.f - lyf) * (1.f - lxf) * mask : 0.f;
      float g01 = (vy0 && vx1) ? (1.f - lyf) * lxf * mask : 0.f;
      float g10 = (vy1 && vx0) ? lyf * (1.f - lxf) * mask : 0.f;
      float g11 = (vy1 && vx1) ? lyf * lxf * mask : 0.f;
      int ly = yi - (h0r - 2), lx = xi - (w0r - 2);
      i32x4 pl;
      pl[0] = (int)((u32)(ly & 0xffff) | ((u32)lx << 16));
      pl[1] = (int)((u32)h2u((h16)g00) | ((u32)h2u((h16)g01) << 16));
      pl[2] = (int)((u32)h2u((h16)g10) | ((u32)h2u((h16)g11) << 16));
      pl[3] = 0;
      plan[tap * 128 + px] = pl;
    }
  }

  // ---- per-thread halo staging slot addresses (registers) ----
  int gsb[4], ldsb[4];
#pragma unroll
  for (int i = 0; i < 4; i++) {
    int s = tid + i * 256;
    int p = s >> 2, scg = s & 3;
    int py = (p * 205) >> 12;  // p/20 for p<400
    int pxx = p - py * HC;
    int gy = min(max(h0r - 2 + py, 0), kH - 1);
    int gx = min(max(w0r - 2 + pxx, 0), kW - 1);
    gsb[i] = (gy * kW + gx) * CIN + (scg << 3);
    ldsb[i] = s * 16;
  }
  const bool full3 = (tid < 192);  // slot tid+768 < 960 (wave 3 idles)

  // ---- stage chunk 0 ----
  {
    i32x4 a0 = *(const i32x4*)(xb + gsb[0]);
    i32x4 a1 = *(const i32x4*)(xb + gsb[1]);
    i32x4 a2 = *(const i32x4*)(xb + gsb[2]);
    *(i32x4*)(lds + ldsb[0]) = a0;
    *(i32x4*)(lds + ldsb[1]) = a1;
    *(i32x4*)(lds + ldsb[2]) = a2;
    if (full3) {
      i32x4 a3 = *(const i32x4*)(xb + gsb[3]);
      *(i32x4*)(lds + ldsb[3]) = a3;
    }
  }

  f32x4 acc[2][NT];
#pragma unroll
  for (int m = 0; m < 2; m++)
#pragma unroll
    for (int nt = 0; nt < NT; nt++) acc[m][nt] = (f32x4){0.f, 0.f, 0.f, 0.f};

  const i32x4* planp = (const i32x4*)(lds + PLAN_OFF);

  int cur = 0;
  for (int ch = 0; ch < NCH; ++ch) {
    __syncthreads();
    const char* bufc = lds + cur * HBYTES;
    const bool has = (ch + 1 < NCH);
    // issue next-chunk loads early (named regs, guarded per wave)
    i32x4 s0, s1, s2, s3;
    if (has) {
      const u16* src = xb + ((ch + 1) << 5);
      s0 = *(const i32x4*)(src + gsb[0]);
      s1 = *(const i32x4*)(src + gsb[1]);
      s2 = *(const i32x4*)(src + gsb[2]);
      if (full3) s3 = *(const i32x4*)(src + gsb[3]);
    }

#pragma unroll
    for (int tap = 0; tap < 9; tap++) {
      h16x8 af[2];
      if (DEFORM) {
#pragma unroll
        for (int m = 0; m < 2; m++) {
          i32x4 pl = planp[tap * 128 + ((wv * 2 + m) << 4) + col];
          int lylx = pl[0];
          int ly = (short)(lylx & 0xffff);
          int lx = lylx >> 16;
          h16 g00 = u2h((u16)((u32)pl[1] & 0xffff));
          h16 g01 = u2h((u16)((u32)pl[1] >> 16));
          h16 g10 = u2h((u16)((u32)pl[2] & 0xffff));
          h16 g11 = u2h((u16)((u32)pl[2] >> 16));
          h16x8 v00, v01, v10, v11;
          if (__builtin_expect(((u32)ly <= (u32)(HR - 2)) &&
                                   ((u32)lx <= (u32)(HC - 2)), 1)) {
            const char* bp8 = bufc + (ly * HC + lx) * 64 + (cg << 4);
            v00 = *(const h16x8*)(bp8);
            v01 = *(const h16x8*)(bp8 + 64);
            v10 = *(const h16x8*)(bp8 + HC * 64);
            v11 = *(const h16x8*)(bp8 + HC * 64 + 64);
          } else {  // rare fallback: global gather with reference clamping
            int y0 = ly + (h0r - 2), x0 = lx + (w0r - 2);
            int y0c = min(max(y0, 0), kH - 1), y1c = min(max(y0 + 1, 0), kH - 1);
            int x0c = min(max(x0, 0), kW - 1), x1c = min(max(x0 + 1, 0), kW - 1);
            const u16* gp = xb + (ch << 5) + (cg << 3);
            v00 = *(const h16x8*)(gp + (size_t)(y0c * kW + x0c) * CIN);
            v01 = *(const h16x8*)(gp + (size_t)(y0c * kW + x1c) * CIN);
            v10 = *(const h16x8*)(gp + (size_t)(y1c * kW + x0c) * CIN);
            v11 = *(const h16x8*)(gp + (size_t)(y1c * kW + x1c) * CIN);
          }
          af[m] = v00 * g00 + v01 * g01 + v10 * g10 + v11 * g11;
        }
      } else {
        const int dy = tap / 3 - 1, dx = tap % 3 - 1;
#pragma unroll
        for (int m = 0; m < 2; m++) {
          const int row = wv * 2 + m;
          int yy = h0r + row + dy, xx = w0r + col + dx;
          bool val = ((u32)yy < (u32)kH) && ((u32)xx < (u32)kW);
          h16x8 v = *(const h16x8*)(bufc + ((row + dy + 2) * HC + col + dx + 2) * 64 +
                                    (cg << 4));
          h16x8 zv = (h16x8){0, 0, 0, 0, 0, 0, 0, 0};
          af[m] = val ? v : zv;
        }
      }
      const u16* bpb = bpack + ((size_t)((ch * 9 + tap) * NTOT) + zb * NT) * 512 +
                       (lane << 3);
#pragma unroll
      for (int nt = 0; nt < NT; nt++) {
        h16x8 bfr = *(const h16x8*)(bpb + (size_t)nt * 512);
        acc[0][nt] = __builtin_amdgcn_mfma_f32_16x16x32_f16(af[0], bfr, acc[0][nt], 0, 0, 0);
        acc[1][nt] = __builtin_amdgcn_mfma_f32_16x16x32_f16(af[1], bfr, acc[1][nt], 0, 0, 0);
      }
    }
    if (has) {
      char* nb = lds + (cur ^ 1) * HBYTES;
      *(i32x4*)(nb + ldsb[0]) = s0;
      *(i32x4*)(nb + ldsb[1]) = s1;
      *(i32x4*)(nb + ldsb[2]) = s2;
      if (full3) *(i32x4*)(nb + ldsb[3]) = s3;
    }
    cur ^= 1;
  }

  // ---- epilogue: D layout n=lane&15(col->o), m-in-frag=4*(lane>>4)+r (->w) --
#pragma unroll
  for (int m = 0; m < 2; m++) {
    const int h = h0r + wv * 2 + m;
#pragma unroll
    for (int nt = 0; nt < NT; nt++) {
      int o = (zb * NT + nt) * 16 + col;
      if (OREAL < NTOT * 16 && o >= OREAL) continue;
      float bb = bias ? bias[o] : 0.f;
#pragma unroll
      for (int r = 0; r < 4; r++) {
        int w = w0r + (cg << 2) + r;
        y[((size_t)(b * OREAL + o)) * kHW + h * kW + w] = acc[m][nt][r] + bb;
      }
    }
  }
}

// ---------------- BN stats (one block per channel) ----------------
__global__ __launch_bounds__(256) void bn_stats(const float* __restrict__ y,
                                                const float* __restrict__ g,
                                                const float* __restrict__ be,
                                                float* __restrict__ ss, int C) {
  const int c = blockIdx.x;
  float s = 0.f, s2 = 0.f;
  for (int b = 0; b < kB; b++) {
    const float4* p = (const float4*)(y + ((size_t)(b * C + c)) * kHW);
    for (int i = threadIdx.x; i < kHW / 4; i += 256) {
      float4 v = p[i];
      s += v.x + v.y + v.z + v.w;
      s2 += v.x * v.x + v.y * v.y + v.z * v.z + v.w * v.w;
    }
  }
#pragma unroll
  for (int o = 32; o > 0; o >>= 1) {
    s += __shfl_down(s, o, 64);
    s2 += __shfl_down(s2, o, 64);
  }
  __shared__ float red[8];
  int lane = threadIdx.x & 63, wid = threadIdx.x >> 6;
  if (lane == 0) {
    red[wid] = s;
    red[4 + wid] = s2;
  }
  __syncthreads();
  if (threadIdx.x == 0) {
    float S = red[0] + red[1] + red[2] + red[3];
    float S2 = red[4] + red[5] + red[6] + red[7];
    const float inv = 1.f / (float)(kB * kHW);
    float mu = S * inv;
    float var = S2 * inv - mu * mu;
    float sc = g[c] * rsqrtf(var + 1e-5f);
    ss[2 * c] = sc;
    ss[2 * c + 1] = be[c] - mu * sc;
  }
}

// ---------------- BN apply + ReLU (final, NCHW in-place) ----------------
__global__ __launch_bounds__(256) void bn_apply(const float* __restrict__ y,
                                                const float* __restrict__ ss,
                                                float* __restrict__ out, int C,
                                                int total4) {
  int idx = blockIdx.x * 256 + threadIdx.x;
  int stride = gridDim.x * 256;
  for (int i = idx; i < total4; i += stride) {
    int c = (i >> 12) % C;
    float sc = ss[2 * c], shf = ss[2 * c + 1];
    float4 v = ((const float4*)y)[i];
    v.x = fmaxf(fmaf(v.x, sc, shf), 0.f);
    v.y = fmaxf(fmaf(v.y, sc, shf), 0.f);
    v.z = fmaxf(fmaf(v.z, sc, shf), 0.f);
    v.w = fmaxf(fmaf(v.w, sc, shf), 0.f);
    ((float4*)out)[i] = v;
  }
}

// ---------------- launch ----------------
extern "C" void kernel_launch(void* const* d_in, const int* in_sizes, int n_in,
                              void* d_out, int out_size, void* d_ws, size_t ws_size,
                              hipStream_t stream) {
  const float* x      = (const float*)d_in[0];
  const float* w_off1 = (const float*)d_in[1];
  const float* b_off1 = (const float*)d_in[2];
  const float* w1     = (const float*)d_in[3];
  const float* b1     = (const float*)d_in[4];
  const float* g1     = (const float*)d_in[5];
  const float* be1    = (const float*)d_in[6];
  const float* w_off2 = (const float*)d_in[7];
  const float* b_off2 = (const float*)d_in[8];
  const float* w2     = (const float*)d_in[9];
  const float* b2     = (const float*)d_in[10];
  const float* g2     = (const float*)d_in[11];
  const float* be2    = (const float*)d_in[12];

  char* ws = (char*)d_ws;
  const size_t XT_OFF  = 0;                        // xt1 (33.5MB); xt2 aliases
  const size_t XT_SZ   = (size_t)kB * kHW * kC1 * 2;
  const size_t OM_OFF  = XT_OFF + XT_SZ;           // 7MB
  const size_t OM_SZ   = (size_t)27 * kB * kHW * 4;
  const size_t BPO1_OFF = OM_OFF + OM_SZ;
  const size_t BPO1_SZ  = (size_t)9 * (kC1 / 32) * 2 * 512 * 2;
  const size_t BP1_OFF = BPO1_OFF + BPO1_SZ;
  const size_t BP1_SZ  = (size_t)9 * (kC1 / 32) * (kM / 16) * 512 * 2;
  const size_t BPO2_OFF = BP1_OFF + BP1_SZ;
  const size_t BPO2_SZ  = (size_t)9 * (kM / 32) * 2 * 512 * 2;
  const size_t BP2_OFF = BPO2_OFF + BPO2_SZ;
  const size_t BP2_SZ  = (size_t)9 * (kM / 32) * (kC2 / 16) * 512 * 2;
  const size_t SS_OFF  = BP2_OFF + BP2_SZ;

  u16* xt1  = (u16*)(ws + XT_OFF);
  u16* xt2  = (u16*)(ws + XT_OFF);  // alias: xt1 dead before xt2 written
  float* om = (float*)(ws + OM_OFF);
  u16* bpo1 = (u16*)(ws + BPO1_OFF);
  u16* bp1  = (u16*)(ws + BP1_OFF);
  u16* bpo2 = (u16*)(ws + BPO2_OFF);
  u16* bp2  = (u16*)(ws + BP2_OFF);
  float* ssb = (float*)(ws + SS_OFF);
  float* y1 = (float*)d_out;
  float* y2 = (float*)d_out;

  // ---------- layer 1 ----------
  to_nhwc<false><<<256, 256, 0, stream>>>(x, nullptr, xt1, kC1);
  prep_bpack<<<(9 * 8 * 2 * 512 + 255) / 256, 256, 0, stream>>>(w_off1, bpo1, kC1, 2, 27);
  prep_bpack<<<(9 * 8 * 8 * 512 + 255) / 256, 256, 0, stream>>>(w1, bp1, kC1, 8, kM);
  dcn_mfma<kC1, 2, 2, 27, false><<<dim3(128, kB, 1), 256, LDS_IMC, stream>>>(
      xt1, nullptr, nullptr, bpo1, nullptr, om);
  dcn_mfma<kC1, 8, 4, kM, true><<<dim3(128, kB, 2), 256, LDS_DEF, stream>>>(
      xt1, om, b_off1, bp1, b1, y1);
  bn_stats<<<kM, 256, 0, stream>>>(y1, g1, be1, ssb, kM);
  to_nhwc<true><<<256, 256, 0, stream>>>(y1, ssb, xt2, kM);

  // ---------- layer 2 ----------
  prep_bpack<<<(9 * 4 * 2 * 512 + 255) / 256, 256, 0, stream>>>(w_off2, bpo2, kM, 2, 27);
  prep_bpack<<<(9 * 4 * 16 * 512 + 255) / 256, 256, 0, stream>>>(w2, bp2, kM, 16, kC2);
  dcn_mfma<kM, 2, 2, 27, false><<<dim3(128, kB, 1), 256, LDS_IMC, stream>>>(
      xt2, nullptr, nullptr, bpo2, nullptr, om);
  dcn_mfma<kM, 16, 4, kC2, true><<<dim3(128, kB, 4), 256, LDS_DEF, stream>>>(
      xt2, om, b_off2, bp2, b2, y2);
  bn_stats<<<kC2, 256, 0, stream>>>(y2, g2, be2, ssb, kC2);
  bn_apply<<<2048, 256, 0, stream>>>(y2, ssb, (float*)d_out, kC2, kB * kC2 * kHW / 4);
}

// Round 8
// 513.610 us; speedup vs baseline: 5.4586x; 1.1110x over previous
//
#include <hip/hip_runtime.h>
#include <hip/hip_bf16.h>
#include <math.h>

// Problem constants (fixed by setup_inputs)
constexpr int kB  = 4;
constexpr int kH  = 128;
constexpr int kW  = 128;
constexpr int kHW = kH * kW;          // 16384
constexpr int kC1 = 256;              // layer1 in channels
constexpr int kM  = 128;              // mid channels
constexpr int kC2 = 256;              // layer2 out channels

typedef unsigned short u16;
typedef unsigned int u32;
typedef _Float16 h16;
typedef __attribute__((ext_vector_type(8))) _Float16 h16x8;
typedef __attribute__((ext_vector_type(4))) float f32x4;
typedef __attribute__((ext_vector_type(4))) int i32x4;

__device__ inline h16 u2h(u16 u) { union { u16 u; h16 h; } c; c.u = u; return c.h; }
__device__ inline u16 h2u(h16 h) { union { u16 u; h16 h; } c; c.h = h; return c.u; }

// Halo LDS swizzle: pixel slot = 64B; 16B sub-slot XORed by pixel bits so a
// quarter-wave (16 consecutive pixels, fixed cg) spreads over all 32 banks
// (bank base = 16*(p&1) + 4*((g^(p>>1))&3) -> 8 groups, 2-way = free).
__device__ inline int hswz(int p, int g) {
  return p * 64 + (((g ^ (p >> 1)) & 3) << 4);
}

// ---------------- NCHW f32 -> NHWC fp16 (optionally fused BN+ReLU) ----------
template <bool BN>
__global__ __launch_bounds__(256) void to_nhwc(const float* __restrict__ src,
                                               const float* __restrict__ ss,
                                               u16* __restrict__ dst, int C) {
  int pxg = blockIdx.x * 256 + threadIdx.x;  // 0 .. B*HW-1
  int b = pxg >> 14, p = pxg & 16383;
  const float* sp = src + (size_t)b * C * kHW + p;
  u16* dp = dst + (size_t)pxg * C;
  for (int c = 0; c < C; c += 2) {
    float v0 = sp[(size_t)c * kHW], v1 = sp[(size_t)(c + 1) * kHW];
    if (BN) {
      v0 = fmaxf(fmaf(v0, ss[2 * c], ss[2 * c + 1]), 0.f);
      v1 = fmaxf(fmaf(v1, ss[2 * c + 2], ss[2 * c + 3]), 0.f);
    }
    u32 pk = (u32)h2u((h16)v0) | ((u32)h2u((h16)v1) << 16);
    *(u32*)(dp + c) = pk;
  }
}

// ------------- weight pre-pack into MFMA B-fragment order (fp16) ------------
// layout: [CIN/32][9][ntiles][64 lanes][8] ; k_local = 8*(lane>>4)+j -> channel,
// n = 16*nt + (lane&15)
__global__ __launch_bounds__(256) void prep_bpack(const float* __restrict__ w,
                                                  u16* __restrict__ bp, int CIN,
                                                  int ntiles, int OREAL) {
  int i = blockIdx.x * 256 + threadIdx.x;
  int total = (CIN / 32) * 9 * ntiles * 512;
  if (i >= total) return;
  int j = i & 7, l = (i >> 3) & 63;
  int rest = i >> 9;
  int nt = rest % ntiles; rest /= ntiles;
  int tap = rest % 9;
  int ch = rest / 9;
  int c = ch * 32 + ((l >> 4) << 3) + j;
  int o = nt * 16 + (l & 15);
  float v = (o < OREAL) ? w[((size_t)o * CIN + c) * 9 + tap] : 0.f;
  bp[i] = h2u((h16)v);
}

// ---------------- fused (deformable) conv via MFMA implicit GEMM ------------
// Block: 8 rows x 16 cols of pixels; 4 waves own 2 rows each. Halo 12x20 px
// per 32-ch chunk in LDS (double-buffered, issue-early/write-late, XOR-swizzled
// layout). Sampling plan in LDS [tap][128px][16B]. A-fragments in fp16 regs,
// B streamed from prepacked global (L2-hot). acc NT<=4; no scratch arrays.
constexpr int HR = 12, HC = 20, HSLOT = HR * HC;   // 240 px
constexpr int HBYTES = HSLOT * 64;                 // 15360 B per buffer
constexpr int PLAN_OFF = 2 * HBYTES;               // plan after 2 halo buffers
constexpr int LDS_DEF = 2 * HBYTES + 9 * 128 * 16; // 49152 B
constexpr int LDS_IMC = 2 * HBYTES;                // 30720 B

template <int CIN, int NTOT, int NT, int OREAL, bool DEFORM>
__global__ __launch_bounds__(256, 3) void dcn_mfma(
    const u16* __restrict__ xt, const float* __restrict__ om,
    const float* __restrict__ boff, const u16* __restrict__ bpack,
    const float* __restrict__ bias, float* __restrict__ y) {
  constexpr int NCH = CIN / 32;
  extern __shared__ char lds[];

  const int tid = threadIdx.x;
  const int lane = tid & 63;
  const int wv = tid >> 6;
  const int col = lane & 15;
  const int cg = lane >> 4;
  const int tile = blockIdx.x, b = blockIdx.y, zb = blockIdx.z;
  // grid.x = 128 tiles: 16 row-tiles x 8 col-tiles
  const int h0r = (tile >> 3) << 3;
  const int w0r = (tile & 7) << 4;
  const u16* xb = xt + (size_t)b * kHW * CIN;

  // ---- sampling plan -> LDS [tap][128 px][16B] ----
  if (DEFORM) {
    i32x4* plan = (i32x4*)(lds + PLAN_OFF);
    for (int e = tid; e < 1152; e += 256) {
      int px = e / 9;                 // pixel id: (row<<4) | colw
      int tap = e - px * 9;
      int h = h0r + (px >> 4), w = w0r + (px & 15);
      const int dy = tap / 3 - 1, dx = tap % 3 - 1;
      const float* omb = om + ((size_t)(b * 27 + tap)) * kHW + h * kW + w;
      float offy = omb[0] + boff[tap];
      float offx = omb[(size_t)9 * kHW] + boff[9 + tap];
      float ml = omb[(size_t)18 * kHW] + boff[18 + tap];
      float mask = 1.f / (1.f + expf(-ml));
      float py = (float)(h + dy) + offy;
      float qx = (float)(w + dx) + offx;
      float fy = floorf(py), fx = floorf(qx);
      float lyf = py - fy, lxf = qx - fx;
      int yi = (int)fy, xi = (int)fx;
      bool vy0 = (yi >= 0) & (yi < kH), vy1 = (yi + 1 >= 0) & (yi + 1 < kH);
      bool vx0 = (xi >= 0) & (xi < kW), vx1 = (xi + 1 >= 0) & (xi + 1 < kW);
      float g00 = (vy0 && vx0) ? (1.f - lyf) * (1.f - lxf) * mask : 0.f;
      float g01 = (vy0 && vx1) ? (1.f - lyf) * lxf * mask : 0.f;
      float g10 = (vy1 && vx0) ? lyf * (1.f - lxf) * mask : 0.f;
      float g11 = (vy1 && vx1) ? lyf * lxf * mask : 0.f;
      int ly = yi - (h0r - 2), lx = xi - (w0r - 2);
      i32x4 pl;
      pl[0] = (int)((u32)(ly & 0xffff) | ((u32)lx << 16));
      pl[1] = (int)((u32)h2u((h16)g00) | ((u32)h2u((h16)g01) << 16));
      pl[2] = (int)((u32)h2u((h16)g10) | ((u32)h2u((h16)g11) << 16));
      pl[3] = 0;
      plan[tap * 128 + px] = pl;
    }
  }

  // ---- per-thread halo staging slot addresses (registers, pre-swizzled) ----
  int gsb[4], ldsb[4];
#pragma unroll
  for (int i = 0; i < 4; i++) {
    int s = tid + i * 256;
    int p = s >> 2, scg = s & 3;
    int py = (p * 205) >> 12;  // p/20 for p<400
    int pxx = p - py * HC;
    int gy = min(max(h0r - 2 + py, 0), kH - 1);
    int gx = min(max(w0r - 2 + pxx, 0), kW - 1);
    gsb[i] = (gy * kW + gx) * CIN + (scg << 3);
    ldsb[i] = hswz(p, scg);
  }
  const bool full3 = (tid < 192);  // slot tid+768 < 960 (wave 3 idles)

  // ---- stage chunk 0 ----
  {
    i32x4 a0 = *(const i32x4*)(xb + gsb[0]);
    i32x4 a1 = *(const i32x4*)(xb + gsb[1]);
    i32x4 a2 = *(const i32x4*)(xb + gsb[2]);
    *(i32x4*)(lds + ldsb[0]) = a0;
    *(i32x4*)(lds + ldsb[1]) = a1;
    *(i32x4*)(lds + ldsb[2]) = a2;
    if (full3) {
      i32x4 a3 = *(const i32x4*)(xb + gsb[3]);
      *(i32x4*)(lds + ldsb[3]) = a3;
    }
  }

  f32x4 acc[2][NT];
#pragma unroll
  for (int m = 0; m < 2; m++)
#pragma unroll
    for (int nt = 0; nt < NT; nt++) acc[m][nt] = (f32x4){0.f, 0.f, 0.f, 0.f};

  const i32x4* planp = (const i32x4*)(lds + PLAN_OFF);

  int cur = 0;
  for (int ch = 0; ch < NCH; ++ch) {
    __syncthreads();
    const char* bufc = lds + cur * HBYTES;
    const bool has = (ch + 1 < NCH);
    // issue next-chunk loads early (named regs, guarded per wave)
    i32x4 s0, s1, s2, s3;
    if (has) {
      const u16* src = xb + ((ch + 1) << 5);
      s0 = *(const i32x4*)(src + gsb[0]);
      s1 = *(const i32x4*)(src + gsb[1]);
      s2 = *(const i32x4*)(src + gsb[2]);
      if (full3) s3 = *(const i32x4*)(src + gsb[3]);
    }

#pragma unroll
    for (int tap = 0; tap < 9; tap++) {
      h16x8 af[2];
      if (DEFORM) {
#pragma unroll
        for (int m = 0; m < 2; m++) {
          i32x4 pl = planp[tap * 128 + ((wv * 2 + m) << 4) + col];
          int lylx = pl[0];
          int ly = (short)(lylx & 0xffff);
          int lx = lylx >> 16;
          h16 g00 = u2h((u16)((u32)pl[1] & 0xffff));
          h16 g01 = u2h((u16)((u32)pl[1] >> 16));
          h16 g10 = u2h((u16)((u32)pl[2] & 0xffff));
          h16 g11 = u2h((u16)((u32)pl[2] >> 16));
          h16x8 v00, v01, v10, v11;
          if (__builtin_expect(((u32)ly <= (u32)(HR - 2)) &&
                                   ((u32)lx <= (u32)(HC - 2)), 1)) {
            int q = ly * HC + lx;
            v00 = *(const h16x8*)(bufc + hswz(q, cg));
            v01 = *(const h16x8*)(bufc + hswz(q + 1, cg));
            v10 = *(const h16x8*)(bufc + hswz(q + HC, cg));
            v11 = *(const h16x8*)(bufc + hswz(q + HC + 1, cg));
          } else {  // rare fallback: global gather with reference clamping
            int y0 = ly + (h0r - 2), x0 = lx + (w0r - 2);
            int y0c = min(max(y0, 0), kH - 1), y1c = min(max(y0 + 1, 0), kH - 1);
            int x0c = min(max(x0, 0), kW - 1), x1c = min(max(x0 + 1, 0), kW - 1);
            const u16* gp = xb + (ch << 5) + (cg << 3);
            v00 = *(const h16x8*)(gp + (size_t)(y0c * kW + x0c) * CIN);
            v01 = *(const h16x8*)(gp + (size_t)(y0c * kW + x1c) * CIN);
            v10 = *(const h16x8*)(gp + (size_t)(y1c * kW + x0c) * CIN);
            v11 = *(const h16x8*)(gp + (size_t)(y1c * kW + x1c) * CIN);
          }
          af[m] = v00 * g00 + v01 * g01 + v10 * g10 + v11 * g11;
        }
      } else {
        const int dy = tap / 3 - 1, dx = tap % 3 - 1;
#pragma unroll
        for (int m = 0; m < 2; m++) {
          const int row = wv * 2 + m;
          int yy = h0r + row + dy, xx = w0r + col + dx;
          bool val = ((u32)yy < (u32)kH) && ((u32)xx < (u32)kW);
          int p2 = (row + dy + 2) * HC + (col + dx + 2);
          h16x8 v = *(const h16x8*)(bufc + hswz(p2, cg));
          h16x8 zv = (h16x8){0, 0, 0, 0, 0, 0, 0, 0};
          af[m] = val ? v : zv;
        }
      }
      const u16* bpb = bpack + ((size_t)((ch * 9 + tap) * NTOT) + zb * NT) * 512 +
                       (lane << 3);
#pragma unroll
      for (int nt = 0; nt < NT; nt++) {
        h16x8 bfr = *(const h16x8*)(bpb + (size_t)nt * 512);
        acc[0][nt] = __builtin_amdgcn_mfma_f32_16x16x32_f16(af[0], bfr, acc[0][nt], 0, 0, 0);
        acc[1][nt] = __builtin_amdgcn_mfma_f32_16x16x32_f16(af[1], bfr, acc[1][nt], 0, 0, 0);
      }
    }
    if (has) {
      char* nb = lds + (cur ^ 1) * HBYTES;
      *(i32x4*)(nb + ldsb[0]) = s0;
      *(i32x4*)(nb + ldsb[1]) = s1;
      *(i32x4*)(nb + ldsb[2]) = s2;
      if (full3) *(i32x4*)(nb + ldsb[3]) = s3;
    }
    cur ^= 1;
  }

  // ---- epilogue: D layout n=lane&15(col->o), m-in-frag=4*(lane>>4)+r (->w) --
#pragma unroll
  for (int m = 0; m < 2; m++) {
    const int h = h0r + wv * 2 + m;
#pragma unroll
    for (int nt = 0; nt < NT; nt++) {
      int o = (zb * NT + nt) * 16 + col;
      if (OREAL < NTOT * 16 && o >= OREAL) continue;
      float bb = bias ? bias[o] : 0.f;
#pragma unroll
      for (int r = 0; r < 4; r++) {
        int w = w0r + (cg << 2) + r;
        y[((size_t)(b * OREAL + o)) * kHW + h * kW + w] = acc[m][nt][r] + bb;
      }
    }
  }
}

// ---------------- BN stats (one block per channel) ----------------
__global__ __launch_bounds__(256) void bn_stats(const float* __restrict__ y,
                                                const float* __restrict__ g,
                                                const float* __restrict__ be,
                                                float* __restrict__ ss, int C) {
  const int c = blockIdx.x;
  float s = 0.f, s2 = 0.f;
  for (int b = 0; b < kB; b++) {
    const float4* p = (const float4*)(y + ((size_t)(b * C + c)) * kHW);
    for (int i = threadIdx.x; i < kHW / 4; i += 256) {
      float4 v = p[i];
      s += v.x + v.y + v.z + v.w;
      s2 += v.x * v.x + v.y * v.y + v.z * v.z + v.w * v.w;
    }
  }
#pragma unroll
  for (int o = 32; o > 0; o >>= 1) {
    s += __shfl_down(s, o, 64);
    s2 += __shfl_down(s2, o, 64);
  }
  __shared__ float red[8];
  int lane = threadIdx.x & 63, wid = threadIdx.x >> 6;
  if (lane == 0) {
    red[wid] = s;
    red[4 + wid] = s2;
  }
  __syncthreads();
  if (threadIdx.x == 0) {
    float S = red[0] + red[1] + red[2] + red[3];
    float S2 = red[4] + red[5] + red[6] + red[7];
    const float inv = 1.f / (float)(kB * kHW);
    float mu = S * inv;
    float var = S2 * inv - mu * mu;
    float sc = g[c] * rsqrtf(var + 1e-5f);
    ss[2 * c] = sc;
    ss[2 * c + 1] = be[c] - mu * sc;
  }
}

// ---------------- BN apply + ReLU (final, NCHW in-place) ----------------
__global__ __launch_bounds__(256) void bn_apply(const float* __restrict__ y,
                                                const float* __restrict__ ss,
                                                float* __restrict__ out, int C,
                                                int total4) {
  int idx = blockIdx.x * 256 + threadIdx.x;
  int stride = gridDim.x * 256;
  for (int i = idx; i < total4; i += stride) {
    int c = (i >> 12) % C;
    float sc = ss[2 * c], shf = ss[2 * c + 1];
    float4 v = ((const float4*)y)[i];
    v.x = fmaxf(fmaf(v.x, sc, shf), 0.f);
    v.y = fmaxf(fmaf(v.y, sc, shf), 0.f);
    v.z = fmaxf(fmaf(v.z, sc, shf), 0.f);
    v.w = fmaxf(fmaf(v.w, sc, shf), 0.f);
    ((float4*)out)[i] = v;
  }
}

// ---------------- launch ----------------
extern "C" void kernel_launch(void* const* d_in, const int* in_sizes, int n_in,
                              void* d_out, int out_size, void* d_ws, size_t ws_size,
                              hipStream_t stream) {
  const float* x      = (const float*)d_in[0];
  const float* w_off1 = (const float*)d_in[1];
  const float* b_off1 = (const float*)d_in[2];
  const float* w1     = (const float*)d_in[3];
  const float* b1     = (const float*)d_in[4];
  const float* g1     = (const float*)d_in[5];
  const float* be1    = (const float*)d_in[6];
  const float* w_off2 = (const float*)d_in[7];
  const float* b_off2 = (const float*)d_in[8];
  const float* w2     = (const float*)d_in[9];
  const float* b2     = (const float*)d_in[10];
  const float* g2     = (const float*)d_in[11];
  const float* be2    = (const float*)d_in[12];

  char* ws = (char*)d_ws;
  const size_t XT_OFF  = 0;                        // xt1 (33.5MB); xt2 aliases
  const size_t XT_SZ   = (size_t)kB * kHW * kC1 * 2;
  const size_t OM_OFF  = XT_OFF + XT_SZ;           // 7MB
  const size_t OM_SZ   = (size_t)27 * kB * kHW * 4;
  const size_t BPO1_OFF = OM_OFF + OM_SZ;
  const size_t BPO1_SZ  = (size_t)9 * (kC1 / 32) * 2 * 512 * 2;
  const size_t BP1_OFF = BPO1_OFF + BPO1_SZ;
  const size_t BP1_SZ  = (size_t)9 * (kC1 / 32) * (kM / 16) * 512 * 2;
  const size_t BPO2_OFF = BP1_OFF + BP1_SZ;
  const size_t BPO2_SZ  = (size_t)9 * (kM / 32) * 2 * 512 * 2;
  const size_t BP2_OFF = BPO2_OFF + BPO2_SZ;
  const size_t BP2_SZ  = (size_t)9 * (kM / 32) * (kC2 / 16) * 512 * 2;
  const size_t SS_OFF  = BP2_OFF + BP2_SZ;

  u16* xt1  = (u16*)(ws + XT_OFF);
  u16* xt2  = (u16*)(ws + XT_OFF);  // alias: xt1 dead before xt2 written
  float* om = (float*)(ws + OM_OFF);
  u16* bpo1 = (u16*)(ws + BPO1_OFF);
  u16* bp1  = (u16*)(ws + BP1_OFF);
  u16* bpo2 = (u16*)(ws + BPO2_OFF);
  u16* bp2  = (u16*)(ws + BP2_OFF);
  float* ssb = (float*)(ws + SS_OFF);
  float* y1 = (float*)d_out;
  float* y2 = (float*)d_out;

  // ---------- layer 1 ----------
  to_nhwc<false><<<256, 256, 0, stream>>>(x, nullptr, xt1, kC1);
  prep_bpack<<<(9 * 8 * 2 * 512 + 255) / 256, 256, 0, stream>>>(w_off1, bpo1, kC1, 2, 27);
  prep_bpack<<<(9 * 8 * 8 * 512 + 255) / 256, 256, 0, stream>>>(w1, bp1, kC1, 8, kM);
  dcn_mfma<kC1, 2, 2, 27, false><<<dim3(128, kB, 1), 256, LDS_IMC, stream>>>(
      xt1, nullptr, nullptr, bpo1, nullptr, om);
  dcn_mfma<kC1, 8, 4, kM, true><<<dim3(128, kB, 2), 256, LDS_DEF, stream>>>(
      xt1, om, b_off1, bp1, b1, y1);
  bn_stats<<<kM, 256, 0, stream>>>(y1, g1, be1, ssb, kM);
  to_nhwc<true><<<256, 256, 0, stream>>>(y1, ssb, xt2, kM);

  // ---------- layer 2 ----------
  prep_bpack<<<(9 * 4 * 2 * 512 + 255) / 256, 256, 0, stream>>>(w_off2, bpo2, kM, 2, 27);
  prep_bpack<<<(9 * 4 * 16 * 512 + 255) / 256, 256, 0, stream>>>(w2, bp2, kM, 16, kC2);
  dcn_mfma<kM, 2, 2, 27, false><<<dim3(128, kB, 1), 256, LDS_IMC, stream>>>(
      xt2, nullptr, nullptr, bpo2, nullptr, om);
  dcn_mfma<kM, 16, 4, kC2, true><<<dim3(128, kB, 4), 256, LDS_DEF, stream>>>(
      xt2, om, b_off2, bp2, b2, y2);
  bn_stats<<<kC2, 256, 0, stream>>>(y2, g2, be2, ssb, kC2);
  bn_apply<<<2048, 256, 0, stream>>>(y2, ssb, (float*)d_out, kC2, kB * kC2 * kHW / 4);
}